// Round 1
// baseline (29731.149 us; speedup 1.0000x reference)
//
#include <hip/hip_runtime.h>
#include <cmath>

#define B_  32
#define T_  250
#define E_  256
#define U_  1024
#define FU_ 4096   // 4*U

__device__ __forceinline__ float sigf(float x) { return 1.f / (1.f + __expf(-x)); }

// ---------------------------------------------------------------------------
// Fused LSTM step: z = x_t @ k0 + h_in @ rk0 + b0; gates; update c, h.
// Grid: 128 blocks (u-tile of 8 each), 256 threads.
// Thread = (b = tid>>3, gate g = (tid>>1)&3, float4 group uf = tid&1).
// Each thread accumulates 4 consecutive z columns for one gate.
// ---------------------------------------------------------------------------
__global__ __launch_bounds__(256) void lstm_step_kernel(
    const int* __restrict__ tokens, const float* __restrict__ emb,
    const float* __restrict__ k0, const float* __restrict__ rk0,
    const float* __restrict__ b0, const float* __restrict__ h_in,
    float* __restrict__ h_out, float* __restrict__ c_st, int t)
{
    __shared__ float a_lds[32][132];   // activation chunk [32 rows][128 cols], padded to 132 for b128 reads
    __shared__ float z_lds[32][32];    // z-tile exchange: [b][g*8 + u_local]

    const int tid = threadIdx.x;
    const int u0  = blockIdx.x * 8;
    const int uf  = tid & 1;
    const int g   = (tid >> 1) & 3;
    const int b   = tid >> 3;

    float ax = 0.f, ay = 0.f, az = 0.f, aw = 0.f;

    // ---- phase 1: x_t @ k0  (K = 256, 2 chunks of 128) ----
    for (int kb = 0; kb < E_; kb += 128) {
        __syncthreads();
        #pragma unroll
        for (int i = 0; i < 16; ++i) {
            int idx = tid + i * 256;
            int row = idx >> 7, col = idx & 127;
            int tok = tokens[row * T_ + t];
            a_lds[row][col] = emb[(size_t)tok * E_ + kb + col];
        }
        __syncthreads();
        const float* wp = k0 + (size_t)kb * FU_ + g * U_ + u0 + uf * 4;
        #pragma unroll 4
        for (int k4 = 0; k4 < 32; ++k4) {
            float4 a4 = *reinterpret_cast<const float4*>(&a_lds[b][k4 * 4]);
            float4 w0 = *reinterpret_cast<const float4*>(wp + (size_t)(k4 * 4 + 0) * FU_);
            float4 w1 = *reinterpret_cast<const float4*>(wp + (size_t)(k4 * 4 + 1) * FU_);
            float4 w2 = *reinterpret_cast<const float4*>(wp + (size_t)(k4 * 4 + 2) * FU_);
            float4 w3 = *reinterpret_cast<const float4*>(wp + (size_t)(k4 * 4 + 3) * FU_);
            ax = fmaf(a4.x, w0.x, ax); ay = fmaf(a4.x, w0.y, ay); az = fmaf(a4.x, w0.z, az); aw = fmaf(a4.x, w0.w, aw);
            ax = fmaf(a4.y, w1.x, ax); ay = fmaf(a4.y, w1.y, ay); az = fmaf(a4.y, w1.z, az); aw = fmaf(a4.y, w1.w, aw);
            ax = fmaf(a4.z, w2.x, ax); ay = fmaf(a4.z, w2.y, ay); az = fmaf(a4.z, w2.z, az); aw = fmaf(a4.z, w2.w, aw);
            ax = fmaf(a4.w, w3.x, ax); ay = fmaf(a4.w, w3.y, ay); az = fmaf(a4.w, w3.z, az); aw = fmaf(a4.w, w3.w, aw);
        }
    }

    // ---- phase 2: h_in @ rk0  (K = 1024, 8 chunks of 128) ----
    for (int kb = 0; kb < U_; kb += 128) {
        __syncthreads();
        #pragma unroll
        for (int i = 0; i < 16; ++i) {
            int idx = tid + i * 256;
            int row = idx >> 7, col = idx & 127;
            a_lds[row][col] = h_in[row * U_ + kb + col];
        }
        __syncthreads();
        const float* wp = rk0 + (size_t)kb * FU_ + g * U_ + u0 + uf * 4;
        #pragma unroll 4
        for (int k4 = 0; k4 < 32; ++k4) {
            float4 a4 = *reinterpret_cast<const float4*>(&a_lds[b][k4 * 4]);
            float4 w0 = *reinterpret_cast<const float4*>(wp + (size_t)(k4 * 4 + 0) * FU_);
            float4 w1 = *reinterpret_cast<const float4*>(wp + (size_t)(k4 * 4 + 1) * FU_);
            float4 w2 = *reinterpret_cast<const float4*>(wp + (size_t)(k4 * 4 + 2) * FU_);
            float4 w3 = *reinterpret_cast<const float4*>(wp + (size_t)(k4 * 4 + 3) * FU_);
            ax = fmaf(a4.x, w0.x, ax); ay = fmaf(a4.x, w0.y, ay); az = fmaf(a4.x, w0.z, az); aw = fmaf(a4.x, w0.w, aw);
            ax = fmaf(a4.y, w1.x, ax); ay = fmaf(a4.y, w1.y, ay); az = fmaf(a4.y, w1.z, az); aw = fmaf(a4.y, w1.w, aw);
            ax = fmaf(a4.z, w2.x, ax); ay = fmaf(a4.z, w2.y, ay); az = fmaf(a4.z, w2.z, az); aw = fmaf(a4.z, w2.w, aw);
            ax = fmaf(a4.w, w3.x, ax); ay = fmaf(a4.w, w3.y, ay); az = fmaf(a4.w, w3.z, az); aw = fmaf(a4.w, w3.w, aw);
        }
    }

    // ---- bias + gate exchange via LDS ----
    const float* bp = b0 + g * U_ + u0 + uf * 4;
    ax += bp[0]; ay += bp[1]; az += bp[2]; aw += bp[3];
    __syncthreads();
    z_lds[b][g * 8 + uf * 4 + 0] = ax;
    z_lds[b][g * 8 + uf * 4 + 1] = ay;
    z_lds[b][g * 8 + uf * 4 + 2] = az;
    z_lds[b][g * 8 + uf * 4 + 3] = aw;
    __syncthreads();

    // ---- pointwise cell update: 256 threads = 32 b x 8 u ----
    int pb = tid >> 3, pu = tid & 7;
    float zi = z_lds[pb][0 * 8 + pu];
    float zf = z_lds[pb][1 * 8 + pu];
    float zg = z_lds[pb][2 * 8 + pu];
    float zo = z_lds[pb][3 * 8 + pu];
    float ii = sigf(zi), ff = sigf(zf), gg = tanhf(zg), oo = sigf(zo);
    int ci = pb * U_ + u0 + pu;
    float cv = ff * c_st[ci] + ii * gg;
    c_st[ci] = cv;
    h_out[ci] = oo * tanhf(cv);
}

// ---------------------------------------------------------------------------
// Cell 1, single step from zero state: z = x_last @ k1 + b1.
// c1 = sig(zi)*tanh(zg); h1 = sig(zo)*tanh(c1).
// ---------------------------------------------------------------------------
__global__ __launch_bounds__(256) void lstm_cell1_kernel(
    const int* __restrict__ tokens, const float* __restrict__ emb,
    const float* __restrict__ k1, const float* __restrict__ b1,
    float* __restrict__ h1)
{
    __shared__ float a_lds[32][132];
    __shared__ float z_lds[32][32];

    const int tid = threadIdx.x;
    const int u0  = blockIdx.x * 8;
    const int uf  = tid & 1;
    const int g   = (tid >> 1) & 3;
    const int b   = tid >> 3;

    float ax = 0.f, ay = 0.f, az = 0.f, aw = 0.f;

    for (int kb = 0; kb < E_; kb += 128) {
        __syncthreads();
        #pragma unroll
        for (int i = 0; i < 16; ++i) {
            int idx = tid + i * 256;
            int row = idx >> 7, col = idx & 127;
            int tok = tokens[row * T_ + (T_ - 1)];
            a_lds[row][col] = emb[(size_t)tok * E_ + kb + col];
        }
        __syncthreads();
        const float* wp = k1 + (size_t)kb * FU_ + g * U_ + u0 + uf * 4;
        #pragma unroll 4
        for (int k4 = 0; k4 < 32; ++k4) {
            float4 a4 = *reinterpret_cast<const float4*>(&a_lds[b][k4 * 4]);
            float4 w0 = *reinterpret_cast<const float4*>(wp + (size_t)(k4 * 4 + 0) * FU_);
            float4 w1 = *reinterpret_cast<const float4*>(wp + (size_t)(k4 * 4 + 1) * FU_);
            float4 w2 = *reinterpret_cast<const float4*>(wp + (size_t)(k4 * 4 + 2) * FU_);
            float4 w3 = *reinterpret_cast<const float4*>(wp + (size_t)(k4 * 4 + 3) * FU_);
            ax = fmaf(a4.x, w0.x, ax); ay = fmaf(a4.x, w0.y, ay); az = fmaf(a4.x, w0.z, az); aw = fmaf(a4.x, w0.w, aw);
            ax = fmaf(a4.y, w1.x, ax); ay = fmaf(a4.y, w1.y, ay); az = fmaf(a4.y, w1.z, az); aw = fmaf(a4.y, w1.w, aw);
            ax = fmaf(a4.z, w2.x, ax); ay = fmaf(a4.z, w2.y, ay); az = fmaf(a4.z, w2.z, az); aw = fmaf(a4.z, w2.w, aw);
            ax = fmaf(a4.w, w3.x, ax); ay = fmaf(a4.w, w3.y, ay); az = fmaf(a4.w, w3.z, az); aw = fmaf(a4.w, w3.w, aw);
        }
    }

    const float* bp = b1 + g * U_ + u0 + uf * 4;
    ax += bp[0]; ay += bp[1]; az += bp[2]; aw += bp[3];
    __syncthreads();
    z_lds[b][g * 8 + uf * 4 + 0] = ax;
    z_lds[b][g * 8 + uf * 4 + 1] = ay;
    z_lds[b][g * 8 + uf * 4 + 2] = az;
    z_lds[b][g * 8 + uf * 4 + 3] = aw;
    __syncthreads();

    int pb = tid >> 3, pu = tid & 7;
    float zi = z_lds[pb][0 * 8 + pu];
    float zg = z_lds[pb][2 * 8 + pu];
    float zo = z_lds[pb][3 * 8 + pu];
    float cv = sigf(zi) * tanhf(zg);             // f*c = 0 since c = 0
    h1[pb * U_ + u0 + pu] = sigf(zo) * tanhf(cv);
}

// ---------------------------------------------------------------------------
// Output projection: out[b] = sigmoid( h0[b,:] @ wout[0:U] + h1[b,:] @ wout[U:2U] + bout )
// ---------------------------------------------------------------------------
__global__ __launch_bounds__(256) void final_kernel(
    const float* __restrict__ h0, const float* __restrict__ h1,
    const float* __restrict__ wout, const float* __restrict__ bout,
    float* __restrict__ out)
{
    const int b = blockIdx.x;
    const int tid = threadIdx.x;
    float s = 0.f;
    for (int u = tid; u < U_; u += 256)
        s += h0[b * U_ + u] * wout[u] + h1[b * U_ + u] * wout[U_ + u];
    #pragma unroll
    for (int off = 32; off > 0; off >>= 1) s += __shfl_down(s, off, 64);
    __shared__ float part[4];
    if ((tid & 63) == 0) part[tid >> 6] = s;
    __syncthreads();
    if (tid == 0) {
        float tot = part[0] + part[1] + part[2] + part[3] + bout[0];
        out[b] = 1.f / (1.f + __expf(-tot));
    }
}

extern "C" void kernel_launch(void* const* d_in, const int* in_sizes, int n_in,
                              void* d_out, int out_size, void* d_ws, size_t ws_size,
                              hipStream_t stream) {
    const int*   tokens = (const int*)  d_in[0];
    const float* emb    = (const float*)d_in[1];
    const float* k0     = (const float*)d_in[2];
    const float* rk0    = (const float*)d_in[3];
    const float* b0     = (const float*)d_in[4];
    const float* k1     = (const float*)d_in[5];
    // d_in[6] = rk1: unused — cell 1 runs from zero state, h @ rk1 == 0.
    const float* b1     = (const float*)d_in[7];
    const float* wout   = (const float*)d_in[8];
    const float* bout   = (const float*)d_in[9];
    float* out = (float*)d_out;

    const int BU = B_ * U_;
    float* hA = (float*)d_ws;        // [0, BU)    : h ping  (also final h0)
    float* c  = hA + BU;             // [BU, 2BU)  : cell state
    float* hB = hA + 2 * BU;         // [2BU, 3BU) : h pong
    float* h1 = hA + 3 * BU;         // [3BU, 4BU) : cell-1 hidden

    // zero h ping + c every call (ws is poisoned 0xAA, not re-poisoned between replays)
    hipMemsetAsync(hA, 0, 2 * (size_t)BU * sizeof(float), stream);

    lstm_cell1_kernel<<<U_ / 8, 256, 0, stream>>>(tokens, emb, k1, b1, h1);

    for (int t = 0; t < T_; ++t) {
        float* hin  = (t & 1) ? hB : hA;
        float* hout = (t & 1) ? hA : hB;
        lstm_step_kernel<<<U_ / 8, 256, 0, stream>>>(tokens, emb, k0, rk0, b0, hin, hout, c, t);
    }
    // T_ = 250 is even -> final h0 lands in hA.

    final_kernel<<<B_, 256, 0, stream>>>(hA, h1, wout, bout, out);
}

// Round 2
// 9054.873 us; speedup vs baseline: 3.2834x; 3.2834x over previous
//
#include <hip/hip_runtime.h>
#include <cmath>

#define B_  32
#define T_  250
#define E_  256
#define U_  1024
#define FU_ 4096   // 4*U
#define NPART 9    // 8 K-slices of h@rk0 + 1 slice of x@k0(+b0)

__device__ __forceinline__ float sigf(float x) { return 1.f / (1.f + __expf(-x)); }

// ---------------------------------------------------------------------------
// S1: z-partials for one step.
// Grid 1152 x 256.
//   blocks [0,1024): h @ rk0, K split 8x128.  bid = ((ks*8+bg)<<4) | ct
//   blocks [1024,1152): x_t @ k0 + b0 (K=256). bid-1024 = (bg<<4) | ct
// ct in low bits => stable blockIdx%8 -> XCD column ownership.
// Thread: lane = tid&63 -> 4 consecutive cols (float4 W loads, fully
// coalesced: wave covers 256 cols = 1 KB/row); warp = tid>>6 -> b row.
// h/emb reads are wave-uniform broadcasts (no LDS anywhere).
// ---------------------------------------------------------------------------
__global__ __launch_bounds__(256) void step_gemm(
    const float* __restrict__ rk0, const float* __restrict__ h,
    const int* __restrict__ tokens, const float* __restrict__ emb,
    const float* __restrict__ k0, const float* __restrict__ b0,
    float* __restrict__ P, int t)
{
    const int tid  = threadIdx.x;
    const int lane = tid & 63;
    const int warp = tid >> 6;
    const int bid  = blockIdx.x;

    if (bid < 1024) {
        const int ct = bid & 15, rest = bid >> 4;
        const int ks = rest >> 3, bg = rest & 7;
        const int b  = bg * 4 + warp;
        const int col = ct * 256 + lane * 4;
        const float* wp = rk0 + (size_t)(ks * 128) * FU_ + col;
        const float* hp = h + b * U_ + ks * 128;
        float4 acc = make_float4(0.f, 0.f, 0.f, 0.f);
        #pragma unroll 4
        for (int k4 = 0; k4 < 32; ++k4) {
            const float4 h4 = *reinterpret_cast<const float4*>(hp + k4 * 4);
            const float4 w0 = *reinterpret_cast<const float4*>(wp + (size_t)(k4 * 4 + 0) * FU_);
            const float4 w1 = *reinterpret_cast<const float4*>(wp + (size_t)(k4 * 4 + 1) * FU_);
            const float4 w2 = *reinterpret_cast<const float4*>(wp + (size_t)(k4 * 4 + 2) * FU_);
            const float4 w3 = *reinterpret_cast<const float4*>(wp + (size_t)(k4 * 4 + 3) * FU_);
            acc.x = fmaf(h4.x, w0.x, acc.x); acc.y = fmaf(h4.x, w0.y, acc.y);
            acc.z = fmaf(h4.x, w0.z, acc.z); acc.w = fmaf(h4.x, w0.w, acc.w);
            acc.x = fmaf(h4.y, w1.x, acc.x); acc.y = fmaf(h4.y, w1.y, acc.y);
            acc.z = fmaf(h4.y, w1.z, acc.z); acc.w = fmaf(h4.y, w1.w, acc.w);
            acc.x = fmaf(h4.z, w2.x, acc.x); acc.y = fmaf(h4.z, w2.y, acc.y);
            acc.z = fmaf(h4.z, w2.z, acc.z); acc.w = fmaf(h4.z, w2.w, acc.w);
            acc.x = fmaf(h4.w, w3.x, acc.x); acc.y = fmaf(h4.w, w3.y, acc.y);
            acc.z = fmaf(h4.w, w3.z, acc.z); acc.w = fmaf(h4.w, w3.w, acc.w);
        }
        *reinterpret_cast<float4*>(P + ((size_t)ks * B_ + b) * FU_ + col) = acc;
    } else {
        const int j  = bid - 1024;
        const int ct = j & 15, bg = j >> 4;
        const int b  = bg * 4 + warp;
        const int col = ct * 256 + lane * 4;
        const int tok = tokens[b * T_ + t];
        const float* wp = k0 + col;
        const float* xp = emb + (size_t)tok * E_;
        float4 acc = *reinterpret_cast<const float4*>(b0 + col);
        #pragma unroll 4
        for (int k4 = 0; k4 < 64; ++k4) {
            const float4 x4 = *reinterpret_cast<const float4*>(xp + k4 * 4);
            const float4 w0 = *reinterpret_cast<const float4*>(wp + (size_t)(k4 * 4 + 0) * FU_);
            const float4 w1 = *reinterpret_cast<const float4*>(wp + (size_t)(k4 * 4 + 1) * FU_);
            const float4 w2 = *reinterpret_cast<const float4*>(wp + (size_t)(k4 * 4 + 2) * FU_);
            const float4 w3 = *reinterpret_cast<const float4*>(wp + (size_t)(k4 * 4 + 3) * FU_);
            acc.x = fmaf(x4.x, w0.x, acc.x); acc.y = fmaf(x4.x, w0.y, acc.y);
            acc.z = fmaf(x4.x, w0.z, acc.z); acc.w = fmaf(x4.x, w0.w, acc.w);
            acc.x = fmaf(x4.y, w1.x, acc.x); acc.y = fmaf(x4.y, w1.y, acc.y);
            acc.z = fmaf(x4.y, w1.z, acc.z); acc.w = fmaf(x4.y, w1.w, acc.w);
            acc.x = fmaf(x4.z, w2.x, acc.x); acc.y = fmaf(x4.z, w2.y, acc.y);
            acc.z = fmaf(x4.z, w2.z, acc.z); acc.w = fmaf(x4.z, w2.w, acc.w);
            acc.x = fmaf(x4.w, w3.x, acc.x); acc.y = fmaf(x4.w, w3.y, acc.y);
            acc.z = fmaf(x4.w, w3.z, acc.z); acc.w = fmaf(x4.w, w3.w, acc.w);
        }
        *reinterpret_cast<float4*>(P + ((size_t)8 * B_ + b) * FU_ + col) = acc;
    }
}

// ---------------------------------------------------------------------------
// S2: combine 9 partials, gates, c/h update (in-place h; stream order is the
// barrier vs this step's S1 readers). Grid 128 x 256, thread = one (b,u).
// ---------------------------------------------------------------------------
__global__ __launch_bounds__(256) void step_point(
    const float* __restrict__ P, float* __restrict__ h, float* __restrict__ c_st)
{
    const int idx = blockIdx.x * 256 + threadIdx.x;   // 0..32767
    const int b = idx >> 10, u = idx & 1023;
    float z[4];
    #pragma unroll
    for (int g = 0; g < 4; ++g) {
        const size_t base = (size_t)b * FU_ + g * U_ + u;
        float s = 0.f;
        #pragma unroll
        for (int p = 0; p < NPART; ++p) s += P[(size_t)p * B_ * FU_ + base];
        z[g] = s;
    }
    const float ii = sigf(z[0]), ff = sigf(z[1]);
    const float gg = tanhf(z[2]), oo = sigf(z[3]);
    const int ci = b * U_ + u;
    const float cv = ff * c_st[ci] + ii * gg;
    c_st[ci] = cv;
    h[ci] = oo * tanhf(cv);
}

// ---------------------------------------------------------------------------
// Cell-1 z: Pc[b][col] = x_last @ k1 + b1. Grid 128 x 256 (x-part structure).
// ---------------------------------------------------------------------------
__global__ __launch_bounds__(256) void cell1_gemm(
    const int* __restrict__ tokens, const float* __restrict__ emb,
    const float* __restrict__ k1, const float* __restrict__ b1,
    float* __restrict__ Pc)
{
    const int tid  = threadIdx.x;
    const int lane = tid & 63;
    const int warp = tid >> 6;
    const int j  = blockIdx.x;
    const int ct = j & 15, bg = j >> 4;
    const int b  = bg * 4 + warp;
    const int col = ct * 256 + lane * 4;
    const int tok = tokens[b * T_ + (T_ - 1)];
    const float* wp = k1 + col;
    const float* xp = emb + (size_t)tok * E_;
    float4 acc = *reinterpret_cast<const float4*>(b1 + col);
    #pragma unroll 4
    for (int k4 = 0; k4 < 64; ++k4) {
        const float4 x4 = *reinterpret_cast<const float4*>(xp + k4 * 4);
        const float4 w0 = *reinterpret_cast<const float4*>(wp + (size_t)(k4 * 4 + 0) * FU_);
        const float4 w1 = *reinterpret_cast<const float4*>(wp + (size_t)(k4 * 4 + 1) * FU_);
        const float4 w2 = *reinterpret_cast<const float4*>(wp + (size_t)(k4 * 4 + 2) * FU_);
        const float4 w3 = *reinterpret_cast<const float4*>(wp + (size_t)(k4 * 4 + 3) * FU_);
        acc.x = fmaf(x4.x, w0.x, acc.x); acc.y = fmaf(x4.x, w0.y, acc.y);
        acc.z = fmaf(x4.x, w0.z, acc.z); acc.w = fmaf(x4.x, w0.w, acc.w);
        acc.x = fmaf(x4.y, w1.x, acc.x); acc.y = fmaf(x4.y, w1.y, acc.y);
        acc.z = fmaf(x4.y, w1.z, acc.z); acc.w = fmaf(x4.y, w1.w, acc.w);
        acc.x = fmaf(x4.z, w2.x, acc.x); acc.y = fmaf(x4.z, w2.y, acc.y);
        acc.z = fmaf(x4.z, w2.z, acc.z); acc.w = fmaf(x4.z, w2.w, acc.w);
        acc.x = fmaf(x4.w, w3.x, acc.x); acc.y = fmaf(x4.w, w3.y, acc.y);
        acc.z = fmaf(x4.w, w3.z, acc.z); acc.w = fmaf(x4.w, w3.w, acc.w);
    }
    *reinterpret_cast<float4*>(Pc + (size_t)b * FU_ + col) = acc;
}

// ---------------------------------------------------------------------------
// Final: out[b] = sigmoid( h0·wout[0:U] + h1·wout[U:2U] + bout ), h1 computed
// on the fly from Pc (cell-1 pointwise fused here; f-gate irrelevant, c=0).
// ---------------------------------------------------------------------------
__global__ __launch_bounds__(256) void final_kernel(
    const float* __restrict__ h0, const float* __restrict__ Pc,
    const float* __restrict__ wout, const float* __restrict__ bout,
    float* __restrict__ out)
{
    const int b = blockIdx.x;
    const int tid = threadIdx.x;
    float s = 0.f;
    for (int u = tid; u < U_; u += 256) {
        const float zi = Pc[(size_t)b * FU_ + u];
        const float zg = Pc[(size_t)b * FU_ + 2 * U_ + u];
        const float zo = Pc[(size_t)b * FU_ + 3 * U_ + u];
        const float c1 = sigf(zi) * tanhf(zg);
        const float h1 = sigf(zo) * tanhf(c1);
        s += h0[b * U_ + u] * wout[u] + h1 * wout[U_ + u];
    }
    #pragma unroll
    for (int off = 32; off > 0; off >>= 1) s += __shfl_down(s, off, 64);
    __shared__ float part[4];
    if ((tid & 63) == 0) part[tid >> 6] = s;
    __syncthreads();
    if (tid == 0) {
        const float tot = part[0] + part[1] + part[2] + part[3] + bout[0];
        out[b] = 1.f / (1.f + __expf(-tot));
    }
}

extern "C" void kernel_launch(void* const* d_in, const int* in_sizes, int n_in,
                              void* d_out, int out_size, void* d_ws, size_t ws_size,
                              hipStream_t stream) {
    const int*   tokens = (const int*)  d_in[0];
    const float* emb    = (const float*)d_in[1];
    const float* k0     = (const float*)d_in[2];
    const float* rk0    = (const float*)d_in[3];
    const float* b0     = (const float*)d_in[4];
    const float* k1     = (const float*)d_in[5];
    // d_in[6] = rk1 unused: cell 1 runs from zero state.
    const float* b1     = (const float*)d_in[7];
    const float* wout   = (const float*)d_in[8];
    const float* bout   = (const float*)d_in[9];
    float* out = (float*)d_out;

    const size_t BU  = (size_t)B_ * U_;        // 32768
    const size_t BFU = (size_t)B_ * FU_;       // 131072
    float* h  = (float*)d_ws;                  // [0, BU)
    float* c  = h + BU;                        // [BU, 2BU)
    float* P  = c + BU;                        // NPART * BFU
    float* Pc = P + (size_t)NPART * BFU;       // BFU
    // total ws use: (2*BU + 10*BFU)*4 B ≈ 5.5 MB

    // h and c must start at zero every call (ws poisoned 0xAA, not re-poisoned)
    hipMemsetAsync(h, 0, 2 * BU * sizeof(float), stream);

    cell1_gemm<<<128, 256, 0, stream>>>(tokens, emb, k1, b1, Pc);

    for (int t = 0; t < T_; ++t) {
        step_gemm<<<1152, 256, 0, stream>>>(rk0, h, tokens, emb, k0, b0, P, t);
        step_point<<<128, 256, 0, stream>>>(P, h, c);
    }

    final_kernel<<<B_, 256, 0, stream>>>(h, Pc, wout, bout, out);
}

// Round 3
// 3343.560 us; speedup vs baseline: 8.8921x; 2.7082x over previous
//
#include <hip/hip_runtime.h>
#include <cmath>

#define B_  32
#define T_  250
#define E_  256
#define U_  1024
#define FU_ 4096   // 4*U
#define S_  16     // K-slices (virtual K = U + E = 1280, 80 per slice)
#define KS_ 80     // K rows per slice
#define CT_ 32     // column tiles
#define CW_ 128    // columns per tile

__device__ __forceinline__ float sigf(float x) { return 1.f / (1.f + __expf(-x)); }

// ---------------------------------------------------------------------------
// Phase A: z-partials. Virtual GEMM a[32][1280] @ W[1280][4096],
//   a = [h | emb[tok]] , W = [rk0 ; k0].
// Grid 512 = (ks<<5)|ct, 256 threads = 4 warps.
// Warp = 8-batch group; lane -> 2 consecutive cols. Thread = 8 b x 2 cols
// (16 acc) so each weight float2 is reused 8x from registers. Activation
// slice staged in LDS, read as wave-uniform float4 broadcast (conflict-free).
// ---------------------------------------------------------------------------
__global__ __launch_bounds__(256) void step_gemm(
    const float* __restrict__ rk0, const float* __restrict__ k0,
    const float* __restrict__ h, const int* __restrict__ tokens,
    const float* __restrict__ emb, float* __restrict__ P, int t)
{
    __shared__ float a_lds[32][KS_];

    const int tid = threadIdx.x;
    const int bid = blockIdx.x;
    const int ct = bid & 31, ks = bid >> 5;
    const int kbase = ks * KS_;

    // stage activation slice: thread b = tid>>3 loads 10 contiguous k
    {
        const int b   = tid >> 3;
        const int kkb = (tid & 7) * 10;
        const int tok = tokens[b * T_ + t];
        const float* xp = emb + (size_t)tok * E_;
        #pragma unroll
        for (int i = 0; i < 10; ++i) {
            const int kg = kbase + kkb + i;
            a_lds[b][kkb + i] = (kg < U_) ? h[b * U_ + kg] : xp[kg - U_];
        }
    }
    __syncthreads();

    const int lane = tid & 63, warp = tid >> 6;
    const int col  = ct * CW_ + lane * 2;
    const int brow = warp * 8;

    float2 acc[8];
    #pragma unroll
    for (int j = 0; j < 8; ++j) acc[j] = make_float2(0.f, 0.f);

    #pragma unroll 2
    for (int kk4 = 0; kk4 < KS_ / 4; ++kk4) {
        float2 w[4];
        #pragma unroll
        for (int r = 0; r < 4; ++r) {
            const int kg = kbase + kk4 * 4 + r;
            const float* wrow = (kg < U_) ? (rk0 + (size_t)kg * FU_)
                                          : (k0 + (size_t)(kg - U_) * FU_);
            w[r] = *reinterpret_cast<const float2*>(wrow + col);
        }
        #pragma unroll
        for (int j = 0; j < 8; ++j) {
            const float4 a4 = *reinterpret_cast<const float4*>(&a_lds[brow + j][kk4 * 4]);
            acc[j].x = fmaf(a4.x, w[0].x, acc[j].x); acc[j].y = fmaf(a4.x, w[0].y, acc[j].y);
            acc[j].x = fmaf(a4.y, w[1].x, acc[j].x); acc[j].y = fmaf(a4.y, w[1].y, acc[j].y);
            acc[j].x = fmaf(a4.z, w[2].x, acc[j].x); acc[j].y = fmaf(a4.z, w[2].y, acc[j].y);
            acc[j].x = fmaf(a4.w, w[3].x, acc[j].x); acc[j].y = fmaf(a4.w, w[3].y, acc[j].y);
        }
    }

    #pragma unroll
    for (int j = 0; j < 8; ++j)
        *reinterpret_cast<float2*>(P + ((size_t)ks * B_ + brow + j) * FU_ + col) = acc[j];
}

// ---------------------------------------------------------------------------
// Phase B: combine 16 partials + bias, gates, c/h update (in-place h).
// Grid 256 x 128 threads; thread = one (b,u).
// ---------------------------------------------------------------------------
__global__ __launch_bounds__(128) void step_point(
    const float* __restrict__ P, const float* __restrict__ b0,
    float* __restrict__ h, float* __restrict__ c_st)
{
    const int idx = blockIdx.x * 128 + threadIdx.x;   // 0..32767
    const int b = idx >> 10, u = idx & 1023;
    float z[4];
    #pragma unroll
    for (int g = 0; g < 4; ++g) {
        float s = b0[g * U_ + u];
        #pragma unroll
        for (int p = 0; p < S_; ++p)
            s += P[((size_t)p * B_ + b) * FU_ + g * U_ + u];
        z[g] = s;
    }
    const float ii = sigf(z[0]), ff = sigf(z[1]);
    const float gg = tanhf(z[2]), oo = sigf(z[3]);
    const int ci = b * U_ + u;
    const float cv = ff * c_st[ci] + ii * gg;
    c_st[ci] = cv;
    h[ci] = oo * tanhf(cv);
}

// ---------------------------------------------------------------------------
// Cell-1 z: Pc[b][col] = x_last @ k1 + b1. Grid 128 x 256.
// ---------------------------------------------------------------------------
__global__ __launch_bounds__(256) void cell1_gemm(
    const int* __restrict__ tokens, const float* __restrict__ emb,
    const float* __restrict__ k1, const float* __restrict__ b1,
    float* __restrict__ Pc)
{
    const int tid  = threadIdx.x;
    const int lane = tid & 63;
    const int warp = tid >> 6;
    const int j  = blockIdx.x;
    const int ct = j & 15, bg = j >> 4;
    const int b  = bg * 4 + warp;
    const int col = ct * 256 + lane * 4;
    const int tok = tokens[b * T_ + (T_ - 1)];
    const float* wp = k1 + col;
    const float* xp = emb + (size_t)tok * E_;
    float4 acc = *reinterpret_cast<const float4*>(b1 + col);
    #pragma unroll 4
    for (int k4 = 0; k4 < 64; ++k4) {
        const float4 x4 = *reinterpret_cast<const float4*>(xp + k4 * 4);
        const float4 w0 = *reinterpret_cast<const float4*>(wp + (size_t)(k4 * 4 + 0) * FU_);
        const float4 w1 = *reinterpret_cast<const float4*>(wp + (size_t)(k4 * 4 + 1) * FU_);
        const float4 w2 = *reinterpret_cast<const float4*>(wp + (size_t)(k4 * 4 + 2) * FU_);
        const float4 w3 = *reinterpret_cast<const float4*>(wp + (size_t)(k4 * 4 + 3) * FU_);
        acc.x = fmaf(x4.x, w0.x, acc.x); acc.y = fmaf(x4.x, w0.y, acc.y);
        acc.z = fmaf(x4.x, w0.z, acc.z); acc.w = fmaf(x4.x, w0.w, acc.w);
        acc.x = fmaf(x4.y, w1.x, acc.x); acc.y = fmaf(x4.y, w1.y, acc.y);
        acc.z = fmaf(x4.y, w1.z, acc.z); acc.w = fmaf(x4.y, w1.w, acc.w);
        acc.x = fmaf(x4.z, w2.x, acc.x); acc.y = fmaf(x4.z, w2.y, acc.y);
        acc.z = fmaf(x4.z, w2.z, acc.z); acc.w = fmaf(x4.z, w2.w, acc.w);
        acc.x = fmaf(x4.w, w3.x, acc.x); acc.y = fmaf(x4.w, w3.y, acc.y);
        acc.z = fmaf(x4.w, w3.z, acc.z); acc.w = fmaf(x4.w, w3.w, acc.w);
    }
    *reinterpret_cast<float4*>(Pc + (size_t)b * FU_ + col) = acc;
}

// ---------------------------------------------------------------------------
// Final: out[b] = sigmoid( h0.wout[0:U] + h1.wout[U:2U] + bout ), h1 on the
// fly from Pc (cell-1 pointwise fused; c=0 so f-gate irrelevant).
// ---------------------------------------------------------------------------
__global__ __launch_bounds__(256) void final_kernel(
    const float* __restrict__ h0, const float* __restrict__ Pc,
    const float* __restrict__ wout, const float* __restrict__ bout,
    float* __restrict__ out)
{
    const int b = blockIdx.x;
    const int tid = threadIdx.x;
    float s = 0.f;
    for (int u = tid; u < U_; u += 256) {
        const float zi = Pc[(size_t)b * FU_ + u];
        const float zg = Pc[(size_t)b * FU_ + 2 * U_ + u];
        const float zo = Pc[(size_t)b * FU_ + 3 * U_ + u];
        const float c1 = sigf(zi) * tanhf(zg);
        const float h1 = sigf(zo) * tanhf(c1);
        s += h0[b * U_ + u] * wout[u] + h1 * wout[U_ + u];
    }
    #pragma unroll
    for (int off = 32; off > 0; off >>= 1) s += __shfl_down(s, off, 64);
    __shared__ float part[4];
    if ((tid & 63) == 0) part[tid >> 6] = s;
    __syncthreads();
    if (tid == 0) {
        const float tot = part[0] + part[1] + part[2] + part[3] + bout[0];
        out[b] = 1.f / (1.f + __expf(-tot));
    }
}

extern "C" void kernel_launch(void* const* d_in, const int* in_sizes, int n_in,
                              void* d_out, int out_size, void* d_ws, size_t ws_size,
                              hipStream_t stream) {
    const int*   tokens = (const int*)  d_in[0];
    const float* emb    = (const float*)d_in[1];
    const float* k0     = (const float*)d_in[2];
    const float* rk0    = (const float*)d_in[3];
    const float* b0     = (const float*)d_in[4];
    const float* k1     = (const float*)d_in[5];
    // d_in[6] = rk1 unused: cell 1 runs from zero state.
    const float* b1     = (const float*)d_in[7];
    const float* wout   = (const float*)d_in[8];
    const float* bout   = (const float*)d_in[9];
    float* out = (float*)d_out;

    const size_t BU  = (size_t)B_ * U_;        // 32768
    const size_t BFU = (size_t)B_ * FU_;       // 131072
    float* h  = (float*)d_ws;                  // [0, BU)
    float* c  = h + BU;                        // [BU, 2BU)
    float* P  = c + BU;                        // S_ * BFU  (8 MB)
    float* Pc = P + (size_t)S_ * BFU;          // BFU
    // ws use: (2*BU + 17*BFU)*4 B ~= 9.2 MB

    // h and c must start at zero every call (ws poisoned 0xAA, not re-poisoned)
    hipMemsetAsync(h, 0, 2 * BU * sizeof(float), stream);

    cell1_gemm<<<128, 256, 0, stream>>>(tokens, emb, k1, b1, Pc);

    for (int t = 0; t < T_; ++t) {
        step_gemm<<<CT_ * S_, 256, 0, stream>>>(rk0, k0, h, tokens, emb, P, t);
        step_point<<<256, 128, 0, stream>>>(P, b0, h, c);
    }

    final_kernel<<<B_, 256, 0, stream>>>(h, Pc, wout, bout, out);
}

// Round 4
// 2643.826 us; speedup vs baseline: 11.2455x; 1.2647x over previous
//
#include <hip/hip_runtime.h>
#include <cmath>

#define B_  32
#define T_  250
#define E_  256
#define U_  1024
#define FU_ 4096   // 4*U
#define VK_ 1280   // virtual K = U + E  ( [rk0 ; k0] )

typedef __attribute__((ext_vector_type(8)))  __bf16 bf16x8;
typedef __attribute__((ext_vector_type(16))) float  f32x16;

__device__ __forceinline__ float sigf(float x) { return 1.f / (1.f + __expf(-x)); }

// ---------------------------------------------------------------------------
// One-time: transpose + hi/lo-split weights.
// WT[j][k] = (k<1024 ? rk0[k][j] : k0[k-1024][j]) as bf16 hi + bf16 lo.
// Grid 2560 = (kt<<6)|jt: jt in [0,64) -> 64 j's; kt in [0,40) -> 32 k's.
// ---------------------------------------------------------------------------
__global__ __launch_bounds__(256) void wsplit_kernel(
    const float* __restrict__ rk0, const float* __restrict__ k0,
    __bf16* __restrict__ wt_hi, __bf16* __restrict__ wt_lo)
{
    __shared__ float tile[32][65];
    const int tid = threadIdx.x;
    const int jt  = blockIdx.x & 63;
    const int kt  = blockIdx.x >> 6;
    const int gk0 = kt * 32;
    const int j0  = jt * 64;

    {   // coalesced load 32 rows x 64 cols
        const int c = tid & 63, r4 = tid >> 6;
        #pragma unroll
        for (int i = 0; i < 8; ++i) {
            const int r  = r4 * 8 + i;
            const int gk = gk0 + r;
            const float* src = (gk < U_) ? (rk0 + (size_t)gk * FU_ + j0 + c)
                                         : (k0 + (size_t)(gk - U_) * FU_ + j0 + c);
            tile[r][c] = *src;
        }
    }
    __syncthreads();
    {   // transposed hi/lo write, 16B per store
        const int j_loc = tid >> 2, kseg = tid & 3;
        bf16x8 hi, lo;
        #pragma unroll
        for (int i = 0; i < 8; ++i) {
            const float  v  = tile[kseg * 8 + i][j_loc];
            const __bf16 hv = (__bf16)v;
            hi[i] = hv;
            lo[i] = (__bf16)(v - (float)hv);
        }
        const size_t off = (size_t)(j0 + j_loc) * VK_ + gk0 + kseg * 8;
        *(bf16x8*)(wt_hi + off) = hi;
        *(bf16x8*)(wt_lo + off) = lo;
    }
}

// ---------------------------------------------------------------------------
// Recurrent step GEMM via MFMA 32x32x16 bf16, 3-product hi/lo (Markidis):
// z = (Ahi+Alo) @ (Whi+Wlo) ~= Ahi@Whi + Alo@Whi + Ahi@Wlo.
// A = [h | emb[tok]] [32][1280]; W = WT^T. Grid 256 = (ks<<7)|ct, 512 thr.
// Block: 32 cols (ct), K-half (ks, 640). Wave w: 80 k = 5 MFMA k-steps.
// A-frag: row=lane&31, k=(lane>>5)*8+j (16B load from h_hi/h_lo, or on-the-fly
// split of fp32 emb). B-frag: col=lane&31, same k -> 16B load from WT (k-major).
// C: row=(reg&3)+8*(reg>>2)+4*(lane>>5), col=lane&31 [m74/m101-verified].
// Cross-wave K-reduce via padded LDS, block writes P[ks] partial.
// ---------------------------------------------------------------------------
__global__ __launch_bounds__(512) void mfma_step(
    const __bf16* __restrict__ wt_hi, const __bf16* __restrict__ wt_lo,
    const __bf16* __restrict__ h_hi, const __bf16* __restrict__ h_lo,
    const int* __restrict__ tokens, const float* __restrict__ emb,
    float* __restrict__ P, int t)
{
    __shared__ float red[64][131];   // [lane][reg*8 + wave], 131 pad: ~2-way banks
    const int tid  = threadIdx.x;
    const int lane = tid & 63;
    const int w    = tid >> 6;            // 8 waves
    const int ct   = blockIdx.x & 127;    // col tile (32 cols)
    const int ks   = blockIdx.x >> 7;     // K half
    const int kbase = ks * 640 + w * 80;

    const int brow = lane & 31;           // A row = batch
    const int khl  = (lane >> 5) * 8;     // k sub-offset within 16-step
    const int col  = ct * 32 + (lane & 31);
    const int tok  = tokens[brow * T_ + t];

    const __bf16* wph = wt_hi + (size_t)col * VK_;
    const __bf16* wpl = wt_lo + (size_t)col * VK_;

    f32x16 acc = {};
    #pragma unroll
    for (int s = 0; s < 5; ++s) {
        const int kf = kbase + s * 16 + khl;   // h/emb branch wave-uniform: 16|1024
        bf16x8 ahi, alo;
        if (kf < U_) {
            ahi = *(const bf16x8*)(h_hi + (size_t)brow * U_ + kf);
            alo = *(const bf16x8*)(h_lo + (size_t)brow * U_ + kf);
        } else {
            const float* ep = emb + (size_t)tok * E_ + (kf - U_);
            #pragma unroll
            for (int j = 0; j < 8; ++j) {
                const float  v  = ep[j];
                const __bf16 hv = (__bf16)v;
                ahi[j] = hv;
                alo[j] = (__bf16)(v - (float)hv);
            }
        }
        const bf16x8 whi = *(const bf16x8*)(wph + kf);
        const bf16x8 wlo = *(const bf16x8*)(wpl + kf);
        acc = __builtin_amdgcn_mfma_f32_32x32x16_bf16(ahi, whi, acc, 0, 0, 0);
        acc = __builtin_amdgcn_mfma_f32_32x32x16_bf16(alo, whi, acc, 0, 0, 0);
        acc = __builtin_amdgcn_mfma_f32_32x32x16_bf16(ahi, wlo, acc, 0, 0, 0);
    }

    #pragma unroll
    for (int r = 0; r < 16; ++r) red[lane][r * 8 + w] = acc[r];
    __syncthreads();

    const int rl = tid >> 3;          // result lane 0..63
    const int r0 = (tid & 7) * 2;     // reg pair
    #pragma unroll
    for (int q = 0; q < 2; ++q) {
        const int rg = r0 + q;
        float s = 0.f;
        #pragma unroll
        for (int i = 0; i < 8; ++i) s += red[rl][rg * 8 + i];
        const int row = (rg & 3) + 8 * (rg >> 2) + 4 * (rl >> 5);
        const int c2  = ct * 32 + (rl & 31);
        P[((size_t)ks * B_ + row) * FU_ + c2] = s;
    }
}

// ---------------------------------------------------------------------------
// Pointwise: z = P0 + P1 + b0; gates; c,h update; emit h as fp32 + bf16 hi/lo.
// Grid 128 x 256; thread = one (b,u).
// ---------------------------------------------------------------------------
__global__ __launch_bounds__(256) void step_point(
    const float* __restrict__ P, const float* __restrict__ b0,
    float* __restrict__ h, float* __restrict__ c_st,
    __bf16* __restrict__ h_hi, __bf16* __restrict__ h_lo)
{
    const int idx = blockIdx.x * 256 + threadIdx.x;   // 0..32767
    const int b = idx >> 10, u = idx & 1023;
    float z[4];
    #pragma unroll
    for (int g = 0; g < 4; ++g) {
        const size_t o = (size_t)b * FU_ + g * U_ + u;
        z[g] = b0[g * U_ + u] + P[o] + P[(size_t)B_ * FU_ + o];
    }
    const float ii = sigf(z[0]), ff = sigf(z[1]);
    const float gg = tanhf(z[2]), oo = sigf(z[3]);
    const int ci = b * U_ + u;
    const float cv = ff * c_st[ci] + ii * gg;
    c_st[ci] = cv;
    const float hv = oo * tanhf(cv);
    h[ci] = hv;
    const __bf16 hh = (__bf16)hv;
    h_hi[ci] = hh;
    h_lo[ci] = (__bf16)(hv - (float)hh);
}

// ---------------------------------------------------------------------------
// Cell-1 z (fp32, off critical path): Pc[b][col] = x_last @ k1 + b1.
// ---------------------------------------------------------------------------
__global__ __launch_bounds__(256) void cell1_gemm(
    const int* __restrict__ tokens, const float* __restrict__ emb,
    const float* __restrict__ k1, const float* __restrict__ b1,
    float* __restrict__ Pc)
{
    const int tid  = threadIdx.x;
    const int lane = tid & 63;
    const int warp = tid >> 6;
    const int j  = blockIdx.x;
    const int ct = j & 15, bg = j >> 4;
    const int b  = bg * 4 + warp;
    const int col = ct * 256 + lane * 4;
    const int tok = tokens[b * T_ + (T_ - 1)];
    const float* wp = k1 + col;
    const float* xp = emb + (size_t)tok * E_;
    float4 acc = *reinterpret_cast<const float4*>(b1 + col);
    #pragma unroll 4
    for (int k4 = 0; k4 < 64; ++k4) {
        const float4 x4 = *reinterpret_cast<const float4*>(xp + k4 * 4);
        const float4 w0 = *reinterpret_cast<const float4*>(wp + (size_t)(k4 * 4 + 0) * FU_);
        const float4 w1 = *reinterpret_cast<const float4*>(wp + (size_t)(k4 * 4 + 1) * FU_);
        const float4 w2 = *reinterpret_cast<const float4*>(wp + (size_t)(k4 * 4 + 2) * FU_);
        const float4 w3 = *reinterpret_cast<const float4*>(wp + (size_t)(k4 * 4 + 3) * FU_);
        acc.x = fmaf(x4.x, w0.x, acc.x); acc.y = fmaf(x4.x, w0.y, acc.y);
        acc.z = fmaf(x4.x, w0.z, acc.z); acc.w = fmaf(x4.x, w0.w, acc.w);
        acc.x = fmaf(x4.y, w1.x, acc.x); acc.y = fmaf(x4.y, w1.y, acc.y);
        acc.z = fmaf(x4.y, w1.z, acc.z); acc.w = fmaf(x4.y, w1.w, acc.w);
        acc.x = fmaf(x4.z, w2.x, acc.x); acc.y = fmaf(x4.z, w2.y, acc.y);
        acc.z = fmaf(x4.z, w2.z, acc.z); acc.w = fmaf(x4.z, w2.w, acc.w);
        acc.x = fmaf(x4.w, w3.x, acc.x); acc.y = fmaf(x4.w, w3.y, acc.y);
        acc.z = fmaf(x4.w, w3.z, acc.z); acc.w = fmaf(x4.w, w3.w, acc.w);
    }
    *reinterpret_cast<float4*>(Pc + (size_t)b * FU_ + col) = acc;
}

// ---------------------------------------------------------------------------
// Final: out[b] = sigmoid( h0.wout[0:U] + h1.wout[U:2U] + bout ); h1 on the
// fly from Pc (cell-1 pointwise fused; c=0 so f-gate irrelevant).
// ---------------------------------------------------------------------------
__global__ __launch_bounds__(256) void final_kernel(
    const float* __restrict__ h0, const float* __restrict__ Pc,
    const float* __restrict__ wout, const float* __restrict__ bout,
    float* __restrict__ out)
{
    const int b = blockIdx.x;
    const int tid = threadIdx.x;
    float s = 0.f;
    for (int u = tid; u < U_; u += 256) {
        const float zi = Pc[(size_t)b * FU_ + u];
        const float zg = Pc[(size_t)b * FU_ + 2 * U_ + u];
        const float zo = Pc[(size_t)b * FU_ + 3 * U_ + u];
        const float c1 = sigf(zi) * tanhf(zg);
        const float h1 = sigf(zo) * tanhf(c1);
        s += h0[b * U_ + u] * wout[u] + h1 * wout[U_ + u];
    }
    #pragma unroll
    for (int off = 32; off > 0; off >>= 1) s += __shfl_down(s, off, 64);
    __shared__ float part[4];
    if ((tid & 63) == 0) part[tid >> 6] = s;
    __syncthreads();
    if (tid == 0) {
        const float tot = part[0] + part[1] + part[2] + part[3] + bout[0];
        out[b] = 1.f / (1.f + __expf(-tot));
    }
}

extern "C" void kernel_launch(void* const* d_in, const int* in_sizes, int n_in,
                              void* d_out, int out_size, void* d_ws, size_t ws_size,
                              hipStream_t stream) {
    const int*   tokens = (const int*)  d_in[0];
    const float* emb    = (const float*)d_in[1];
    const float* k0     = (const float*)d_in[2];
    const float* rk0    = (const float*)d_in[3];
    const float* b0     = (const float*)d_in[4];
    const float* k1     = (const float*)d_in[5];
    // d_in[6] = rk1 unused: cell 1 runs from zero state.
    const float* b1     = (const float*)d_in[7];
    const float* wout   = (const float*)d_in[8];
    const float* bout   = (const float*)d_in[9];
    float* out = (float*)d_out;

    const size_t BU  = (size_t)B_ * U_;        // 32768
    const size_t BFU = (size_t)B_ * FU_;       // 131072
    const size_t WSZ = (size_t)FU_ * VK_;      // 5242880

    float* h  = (float*)d_ws;                  // fp32 h (for final)
    float* c  = h + BU;                        // fp32 cell state
    float* P  = c + BU;                        // [2][32][4096] partials
    float* Pc = P + 2 * BFU;                   // cell-1 z
    __bf16* h_hi  = (__bf16*)(Pc + BFU);
    __bf16* h_lo  = h_hi + BU;
    __bf16* wt_hi = h_lo + BU;                 // [4096][1280]
    __bf16* wt_lo = wt_hi + WSZ;
    // total ws use ~= 22.9 MB

    // zero state every call (ws poisoned 0xAA, not re-poisoned between replays)
    hipMemsetAsync(h, 0, 2 * BU * sizeof(float), stream);       // h, c
    hipMemsetAsync(h_hi, 0, 2 * BU * sizeof(__bf16), stream);   // h_hi, h_lo

    wsplit_kernel<<<2560, 256, 0, stream>>>(rk0, k0, wt_hi, wt_lo);
    cell1_gemm<<<128, 256, 0, stream>>>(tokens, emb, k1, b1, Pc);

    for (int t = 0; t < T_; ++t) {
        mfma_step<<<256, 512, 0, stream>>>(wt_hi, wt_lo, h_hi, h_lo,
                                           tokens, emb, P, t);
        step_point<<<128, 256, 0, stream>>>(P, b0, h, c, h_hi, h_lo);
    }

    final_kernel<<<B_, 256, 0, stream>>>(h, Pc, wout, bout, out);
}